// Round 2
// baseline (563.369 us; speedup 1.0000x reference)
//
#include <hip/hip_runtime.h>
#include <hip/hip_bf16.h>
#include <math.h>

#define NODES 73728   // B*T*N = 128*64*9
#define BB    128
#define TT    64
#define NN    9
#define LDX   256
#define E_REAL 203648.0f
#define NARR  33

typedef _Float16 half8 __attribute__((ext_vector_type(8)));
typedef _Float16 half4 __attribute__((ext_vector_type(4)));
typedef _Float16 half2 __attribute__((ext_vector_type(2)));
typedef float f32x4 __attribute__((ext_vector_type(4)));

__device__ __forceinline__ float bfdec(unsigned short u) {
  return __uint_as_float(((unsigned)u) << 16);
}
__device__ __forceinline__ unsigned short f2h(float x) {
  _Float16 h = (_Float16)x;
  return __builtin_bit_cast(unsigned short, h);
}

// 2-wide f16 dot with f32 accumulator (v_dot2_f32_f16)
#if __has_builtin(__builtin_amdgcn_fdot2)
#define DOT2(a, b, c) __builtin_amdgcn_fdot2((a), (b), (c), false)
#else
#define DOT2(a, b, c) ((c) + (float)(a)[0] * (float)(b)[0] + (float)(a)[1] * (float)(b)[1])
#endif
#define D2(v, k) __builtin_shufflevector((v), (v), 2 * (k), 2 * (k) + 1)

// ---------------- dtype detector ----------------
__global__ __launch_bounds__(256) void detect_kernel(const unsigned short* __restrict__ raw,
                                                     float* __restrict__ flag) {
  __shared__ float sm[256];
  float mx = 0.f;
  for (int i = threadIdx.x; i < 2048; i += 256) mx = fmaxf(mx, fabsf(bfdec(raw[2 * i])));
  sm[threadIdx.x] = mx;
  __syncthreads();
  for (int s = 128; s > 0; s >>= 1) {
    if (threadIdx.x < s) sm[threadIdx.x] = fmaxf(sm[threadIdx.x], sm[threadIdx.x + s]);
    __syncthreads();
  }
  if (threadIdx.x == 0) flag[0] = (sm[0] > 1000.f) ? 1.f : 0.f;
}

// ---------------- convert all inputs to fp32 + f16 shadow in ONE pass ----------------
struct CvtArgs { const void* src[NARR]; int size[NARR]; int off[NARR]; };

__global__ __launch_bounds__(256) void convert_kernel(CvtArgs a, const float* __restrict__ flag,
                                                      float* __restrict__ dst,
                                                      _Float16* __restrict__ dsth) {
  int i = blockIdx.y;
  int sz = a.size[i];
  bool isf32 = flag[0] > 0.5f;
  const float* sf = (const float*)a.src[i];
  const unsigned short* sh = (const unsigned short*)a.src[i];
  float* d = dst + a.off[i];
  _Float16* dh = dsth + a.off[i];
  for (int j = blockIdx.x * 256 + threadIdx.x; j < sz; j += gridDim.x * 256) {
    float v = isf32 ? sf[j] : bfdec(sh[j]);
    d[j] = v;
    dh[j] = (_Float16)v;
  }
}

// ---------------- encoder (one block per node, thread d) ----------------
__global__ __launch_bounds__(128) void encoder_simple(const float* __restrict__ nf,
    const float* __restrict__ encW, const float* __restrict__ encb, _Float16* __restrict__ Xh) {
  int v = blockIdx.x, d = threadIdx.x, n = v % NN;
  float f[14];
#pragma unroll
  for (int i = 0; i < 10; i++) f[i] = nf[(size_t)v * 10 + i];
  f[10] = (n < 7) ? 1.f : 0.f;
  f[11] = (n == 7) ? 1.f : 0.f;
  f[12] = (n == 8) ? 1.f : 0.f;
  f[13] = fabsf((float)(n - 7));
  const float* w = &encW[((size_t)n * 128 + d) * 14];
  float s = encb[n * 128 + d];
#pragma unroll
  for (int i = 0; i < 14; i++) s = fmaf(f[i], w[i], s);
  Xh[(size_t)v * LDX + d] = (_Float16)s;
}

// ---------------- fill ----------------
__global__ __launch_bounds__(256) void fill_kernel(const float* __restrict__ nf,
                                                   float* __restrict__ fill) {
  __shared__ float sx[256], sy[256], sz[256];
  int tid = threadIdx.x;
  float ax = 0.f, ay = 0.f, az = 0.f;
  for (int p = tid; p < BB * NN; p += 256) {
    int b = p / NN, n = p - b * NN;
    size_t late  = (((size_t)b * TT + (TT - 1)) * NN + n) * 10;
    size_t early = (((size_t)b * TT) * NN + n) * 10;
    ax += nf[late + 0] - nf[early + 0];
    ay += nf[late + 1] - nf[early + 1];
    az += nf[late + 2] - nf[early + 2];
  }
  sx[tid] = ax; sy[tid] = ay; sz[tid] = az;
  __syncthreads();
  for (int s = 128; s > 0; s >>= 1) {
    if (tid < s) { sx[tid] += sx[tid + s]; sy[tid] += sy[tid + s]; sz[tid] += sz[tid + s]; }
    __syncthreads();
  }
  if (tid == 0) { fill[0] = sx[0] / E_REAL; fill[1] = sy[0] / E_REAL; fill[2] = sz[0] / E_REAL; }
}

// ================= MFMA GEMM: 32 rows x 256 cols per block, 256 threads =================
#define LDA 40
struct GemmSh32 { _Float16 A[32 * LDA]; _Float16 B[256 * LDA]; };

__device__ __forceinline__ void mfma_gemm32(const _Float16* __restrict__ x,
    const _Float16* __restrict__ W, int K, int row0, int tid,
    _Float16* shA, _Float16* shB, f32x4 (&acc)[2][4]) {
  int lane = tid & 63, wv = tid >> 6;
  int quad = lane >> 4, mrow = lane & 15;
  int ar = tid >> 2, ak = (tid & 3) << 3;
  for (int k0 = 0; k0 < K; k0 += 32) {
    if (tid < 128)
      *(half8*)&shA[ar * LDA + ak] = *(const half8*)&x[(size_t)(row0 + ar) * LDX + k0 + ak];
#pragma unroll
    for (int j = 0; j < 4; j++)
      *(half8*)&shB[tid * LDA + (j << 3)] = *(const half8*)&W[(size_t)tid * K + k0 + (j << 3)];
    __syncthreads();
    half8 af[2], bfr[4];
#pragma unroll
    for (int rt = 0; rt < 2; rt++)
      af[rt] = *(const half8*)&shA[(rt * 16 + mrow) * LDA + quad * 8];
#pragma unroll
    for (int ct = 0; ct < 4; ct++)
      bfr[ct] = *(const half8*)&shB[(wv * 64 + ct * 16 + mrow) * LDA + quad * 8];
#pragma unroll
    for (int rt = 0; rt < 2; rt++)
#pragma unroll
      for (int ct = 0; ct < 4; ct++)
        acc[rt][ct] = __builtin_amdgcn_mfma_f32_16x16x32_f16(af[rt], bfr[ct], acc[rt][ct], 0, 0, 0);
    __syncthreads();
  }
}

// write acc (+bias) into epilogue LDS buffer as f16.  C/D map: col=lane&15, row=quad*4+reg
#define ACC32_TO_EPI(ACC, EPI, BIASPTR)                                         \
  {                                                                             \
    int lane_ = tid & 63, wv_ = tid >> 6, quad_ = lane_ >> 4, mrow_ = lane_ & 15; \
    _Pragma("unroll")                                                           \
    for (int rt = 0; rt < 2; rt++)                                              \
      _Pragma("unroll")                                                         \
      for (int ct = 0; ct < 4; ct++) {                                          \
        int col = wv_ * 64 + ct * 16 + mrow_;                                   \
        float bs_ = BIASPTR[col];                                               \
        _Pragma("unroll")                                                       \
        for (int r = 0; r < 4; r++)                                             \
          EPI[rt * 16 + quad_ * 4 + r][col] = f2h(ACC[rt][ct][r] + bs_);        \
      }                                                                         \
  }                                                                             \
  __syncthreads();

// ---------------- XL = X @ lW.T + lb -> f16 ----------------
__global__ __launch_bounds__(256, 4) void gemm_xl_kernel(const _Float16* __restrict__ x, int K,
    const _Float16* __restrict__ W, const float* __restrict__ bias, _Float16* __restrict__ XL) {
  __shared__ union { GemmSh32 st; unsigned short epi[32][264]; } sh;
  int tid = threadIdx.x;
  int row0 = blockIdx.x * 32;
  f32x4 acc[2][4] = {};
  mfma_gemm32(x, W, K, row0, tid, sh.st.A, sh.st.B, acc);
  ACC32_TO_EPI(acc, sh.epi, bias)
  int r = tid >> 3, cbase = (tid & 7) << 5;
#pragma unroll
  for (int j = 0; j < 4; j++)
    *(uint4*)&XL[(size_t)(row0 + r) * LDX + cbase + (j << 3)] =
        *(const uint4*)&sh.epi[r][cbase + (j << 3)];
}

// ============ fused per-layer kernel: XR GEMM + edges/softmax/agg (LDS) + sW GEMM + LN/SiLU ============
__global__ __launch_bounds__(256, 4) void fused_kernel(_Float16* __restrict__ Xh, int K,
    const _Float16* __restrict__ rW, const float* __restrict__ rb,
    const _Float16* __restrict__ XL, const float* __restrict__ nf, const float* __restrict__ fill,
    const _Float16* __restrict__ atth, const _Float16* __restrict__ ewh,
    const _Float16* __restrict__ sW, const float* __restrict__ sb,
    const float* __restrict__ gamma, const float* __restrict__ beta,
    float* pool_out, int do_pool) {
  __shared__ struct {
    union { GemmSh32 st; float pacc[4][256]; } a;
    unsigned short epi[32][264];       // XR -> AGG (in place) -> XO (in place)
  } sh;
  int tid = threadIdx.x;
  int row0 = blockIdx.x * 32;
  int wave = tid >> 6, lane = tid & 63;

  // ---- phase 1: XR = X @ rW.T + rb -> epi ----
  {
    f32x4 acc[2][4] = {};
    mfma_gemm32(Xh, rW, K, row0, tid, sh.a.st.A, sh.a.st.B, acc);
    ACC32_TO_EPI(acc, sh.epi, rb)
  }

  // ---- phase 2: edge logits + softmax + aggregation (AGG overwrites epi in place) ----
  {
    int g = lane >> 4;          // node sub-index (0..3)
    int l = lane & 15;          // channel slab: 16 ch per lane
    int ch0 = l << 4;
    half8 att_lo = *(const half8*)&atth[ch0];
    half8 att_hi = *(const half8*)&atth[ch0 + 8];
    half8 ew0l, ew1l, ew2l, ew0h, ew1h, ew2h;
#pragma unroll
    for (int j = 0; j < 8; j++) {
      ew0l[j] = ewh[(ch0 + j) * 3 + 0];      ew0h[j] = ewh[(ch0 + 8 + j) * 3 + 0];
      ew1l[j] = ewh[(ch0 + j) * 3 + 1];      ew1h[j] = ewh[(ch0 + 8 + j) * 3 + 1];
      ew2l[j] = ewh[(ch0 + j) * 3 + 2];      ew2h[j] = ewh[(ch0 + 8 + j) * 3 + 2];
    }
    float f0 = fill[0], f1 = fill[1], f2 = fill[2];
    for (int it = 0; it < 2; it++) {
      int r = wave * 8 + it * 4 + g;
      int v = row0 + r;
      int n = v % NN;
      int t = (v / NN) & 63;
      int srcs[4] = { v, (n > 0) ? v - 1 : v, (n < NN - 1) ? v + 1 : v, (t > 0) ? v - NN : v };
      bool valid[4] = { true, n > 0, n < NN - 1, t > 0 };
      float px = nf[(size_t)v * 10 + 0];
      float py = nf[(size_t)v * 10 + 1];
      float pz = nf[(size_t)v * 10 + 2];
      _Float16* erow = (_Float16*)sh.epi[r];
      half8 xr_lo = *(const half8*)&erow[ch0];
      half8 xr_hi = *(const half8*)&erow[ch0 + 8];
      half8 xls[4][2];
      float lg[4];
#pragma unroll
      for (int e = 0; e < 4; e++) {
        int s = srcs[e];
        float a0, a1, a2;
        if (e == 0) { a0 = f0; a1 = f1; a2 = f2; }
        else {
          a0 = px - nf[(size_t)s * 10 + 0];
          a1 = py - nf[(size_t)s * 10 + 1];
          a2 = pz - nf[(size_t)s * 10 + 2];
        }
        _Float16 h0 = (_Float16)a0, h1 = (_Float16)a1, h2 = (_Float16)a2;
        xls[e][0] = *(const half8*)&XL[(size_t)s * LDX + ch0];
        xls[e][1] = *(const half8*)&XL[(size_t)s * LDX + ch0 + 8];
        half8 mlo = (xr_lo + xls[e][0]) + (ew0l * h0 + ew1l * h1 + ew2l * h2);
        half8 mhi = (xr_hi + xls[e][1]) + (ew0h * h0 + ew1h * h1 + ew2h * h2);
        mlo = __builtin_elementwise_max(mlo, mlo * (_Float16)0.2f);   // leaky 0.2 exact
        mhi = __builtin_elementwise_max(mhi, mhi * (_Float16)0.2f);
        float p = 0.f;
        p = DOT2(D2(mlo, 0), D2(att_lo, 0), p);
        p = DOT2(D2(mlo, 1), D2(att_lo, 1), p);
        p = DOT2(D2(mlo, 2), D2(att_lo, 2), p);
        p = DOT2(D2(mlo, 3), D2(att_lo, 3), p);
        p = DOT2(D2(mhi, 0), D2(att_hi, 0), p);
        p = DOT2(D2(mhi, 1), D2(att_hi, 1), p);
        p = DOT2(D2(mhi, 2), D2(att_hi, 2), p);
        p = DOT2(D2(mhi, 3), D2(att_hi, 3), p);
        p += __shfl_xor(p, 1);        // head spans 4 lanes (64 ch)
        p += __shfl_xor(p, 2);
        lg[e] = valid[e] ? p : -1e30f;
      }
      float mx = fmaxf(fmaxf(lg[0], lg[1]), fmaxf(lg[2], lg[3]));
      float w0 = __expf(lg[0] - mx), w1 = __expf(lg[1] - mx);
      float w2 = __expf(lg[2] - mx), w3 = __expf(lg[3] - mx);
      float inv = 1.f / (w0 + w1 + w2 + w3);
      float wv4[4] = { w0, w1, w2, w3 };
      half8 agg_lo = { 0, 0, 0, 0, 0, 0, 0, 0 };
      half8 agg_hi = { 0, 0, 0, 0, 0, 0, 0, 0 };
#pragma unroll
      for (int e = 0; e < 4; e++) {
        _Float16 wh = (_Float16)(wv4[e] * inv);   // invalid edges: exactly 0
        agg_lo = agg_lo + xls[e][0] * wh;
        agg_hi = agg_hi + xls[e][1] * wh;
      }
      // in-place: this lane is the only reader/writer of this slab
      *(half8*)&erow[ch0] = agg_lo;
      *(half8*)&erow[ch0 + 8] = agg_hi;
    }
  }
  // no explicit barrier needed: the sW GEMM's internal __syncthreads orders
  // all edge-phase epi writes before the epilogue's epi reads.

  // ---- phase 3: XO = X @ sW.T + sb + AGG -> epi (in place) ----
  {
    f32x4 acc[2][4] = {};
    mfma_gemm32(Xh, sW, K, row0, tid, sh.a.st.A, sh.a.st.B, acc);
    int quad_ = lane >> 4, mrow_ = lane & 15;
#pragma unroll
    for (int rt = 0; rt < 2; rt++)
#pragma unroll
      for (int ct = 0; ct < 4; ct++) {
        int col = wave * 64 + ct * 16 + mrow_;
        float bs = sb[col];
#pragma unroll
        for (int rr = 0; rr < 4; rr++) {
          int row = rt * 16 + quad_ * 4 + rr;
          _Float16 ag = *(const _Float16*)&sh.epi[row][col];
          sh.epi[row][col] = f2h(acc[rt][ct][rr] + bs + (float)ag);
        }
      }
  }
  __syncthreads();

  // ---- phase 4: LayerNorm + SiLU + write Xh (+ pool) ----
  {
    int cc = lane << 2;
    float gm[4], bt[4];
#pragma unroll
    for (int i = 0; i < 4; i++) { gm[i] = gamma[cc + i]; bt[i] = beta[cc + i]; }
    float psum[4] = { 0.f, 0.f, 0.f, 0.f };
    for (int k = 0; k < 8; k++) {
      int r = wave * 8 + k;
      int v = row0 + r;
      const _Float16* erow = (const _Float16*)sh.epi[r];
      half4 x4 = *(const half4*)&erow[cc];
      float xv[4] = { (float)x4[0], (float)x4[1], (float)x4[2], (float)x4[3] };
      float s1 = xv[0] + xv[1] + xv[2] + xv[3];
#pragma unroll
      for (int off = 1; off < 64; off <<= 1) s1 += __shfl_xor(s1, off);
      float mu = s1 * (1.f / 256.f);
      float s2 = 0.f;
#pragma unroll
      for (int i = 0; i < 4; i++) { float d = xv[i] - mu; s2 = fmaf(d, d, s2); }
#pragma unroll
      for (int off = 1; off < 64; off <<= 1) s2 += __shfl_xor(s2, off);
      float rs = rsqrtf(s2 * (1.f / 256.f) + 1e-5f);
      half4 o;
#pragma unroll
      for (int i = 0; i < 4; i++) {
        float y = (xv[i] - mu) * rs * gm[i] + bt[i];
        float z = y * (1.f / (1.f + __expf(-y)));   // SiLU
        o[i] = (_Float16)z;
        psum[i] += z;
      }
      *(half4*)&Xh[(size_t)v * LDX + cc] = o;
    }
    if (do_pool) {
      __syncthreads();                 // GEMM staging done; reuse st as pacc
#pragma unroll
      for (int i = 0; i < 4; i++) sh.a.pacc[wave][cc + i] = psum[i];
      __syncthreads();
      if (wave == 0) {
        int b = row0 / 576;            // 576 = 9*64: block fully within one batch
#pragma unroll
        for (int i = 0; i < 4; i++) {
          float s = sh.a.pacc[0][cc + i] + sh.a.pacc[1][cc + i] +
                    sh.a.pacc[2][cc + i] + sh.a.pacc[3][cc + i];
          atomicAdd(&pool_out[b * 256 + cc + i], s * (1.f / 576.f));
        }
      }
    }
  }
}

extern "C" void kernel_launch(void* const* d_in, const int* in_sizes, int n_in,
                              void* d_out, int out_size, void* d_ws, size_t ws_size,
                              hipStream_t stream) {
  static const int kSize[NARR] = {
    737280, 16128, 1152,
    32768, 256, 32768, 256, 256, 768, 32768, 256, 256, 256,   // layer 0 (K=128)
    65536, 256, 65536, 256, 256, 768, 65536, 256, 256, 256,   // layer 1 (K=256)
    65536, 256, 65536, 256, 256, 768, 65536, 256, 256, 256    // layer 2 (K=256)
  };
  if (n_in != NARR || out_size != BB * 256) return;
  for (int i = 0; i < NARR; i++) if (in_sizes[i] != kSize[i]) return;

  CvtArgs ca;
  int off = 0;
  for (int i = 0; i < NARR; i++) { ca.src[i] = d_in[i]; ca.size[i] = kSize[i]; ca.off[i] = off; off += kSize[i]; }
  const int PRM_ELEMS = off;   // 1,252,992

  const size_t OFF_FLAG = 0;
  const size_t OFF_FILL = 16;
  const size_t OFF_PRM  = 256;
  const size_t OFF_PRMH = OFF_PRM + (size_t)PRM_ELEMS * 4;     // f16 shadow
  const size_t OFF_XL   = OFF_PRMH + (size_t)PRM_ELEMS * 2;    // XL f16
  const size_t OFF_XH   = OFF_XL + (size_t)NODES * LDX * 2;    // X f16
  const size_t NEED     = OFF_XH + (size_t)NODES * LDX * 2;    // ~80 MiB
  if (ws_size < NEED) return;

  char* ws = (char*)d_ws;
  float*     flag = (float*)(ws + OFF_FLAG);
  float*     fill = (float*)(ws + OFF_FILL);
  float*     prm  = (float*)(ws + OFF_PRM);
  _Float16*  prmh = (_Float16*)(ws + OFF_PRMH);
  _Float16*  XL   = (_Float16*)(ws + OFF_XL);
  _Float16*  Xh   = (_Float16*)(ws + OFF_XH);

  hipMemsetAsync(d_out, 0, (size_t)out_size * 4, stream);   // pool accumulator
  detect_kernel<<<1, 256, 0, stream>>>((const unsigned short*)d_in[0], flag);
  convert_kernel<<<dim3(360, NARR), 256, 0, stream>>>(ca, flag, prm, prmh);

  const float* nf   = prm + ca.off[0];
  const float* encW = prm + ca.off[1];
  const float* encb = prm + ca.off[2];

  encoder_simple<<<NODES, 128, 0, stream>>>(nf, encW, encb, Xh);
  fill_kernel<<<1, 256, 0, stream>>>(nf, fill);

  int K = 128;
  for (int L = 0; L < 3; L++) {
    const _Float16* lWh = prmh + ca.off[3 + L * 10 + 0];
    const float*    lb  = prm  + ca.off[3 + L * 10 + 1];
    const _Float16* rWh = prmh + ca.off[3 + L * 10 + 2];
    const float*    rb  = prm  + ca.off[3 + L * 10 + 3];
    const _Float16* atth= prmh + ca.off[3 + L * 10 + 4];
    const _Float16* ewhp= prmh + ca.off[3 + L * 10 + 5];
    const _Float16* sWh = prmh + ca.off[3 + L * 10 + 6];
    const float*    sb  = prm  + ca.off[3 + L * 10 + 7];
    const float*    g   = prm  + ca.off[3 + L * 10 + 8];
    const float*    b   = prm  + ca.off[3 + L * 10 + 9];
    gemm_xl_kernel<<<NODES / 32, 256, 0, stream>>>(Xh, K, lWh, lb, XL);
    fused_kernel<<<NODES / 32, 256, 0, stream>>>(Xh, K, rWh, rb, XL, nf, fill, atth, ewhp,
                                                 sWh, sb, g, b, (float*)d_out, (L == 2) ? 1 : 0);
    K = 256;
  }
}

// Round 3
// 535.000 us; speedup vs baseline: 1.0530x; 1.0530x over previous
//
#include <hip/hip_runtime.h>
#include <hip/hip_bf16.h>
#include <math.h>

#define NODES 73728   // B*T*N = 128*64*9
#define BB    128
#define TT    64
#define NN    9
#define LDX   256
#define E_REAL 203648.0f
#define NARR  33

typedef _Float16 half8 __attribute__((ext_vector_type(8)));
typedef _Float16 half4 __attribute__((ext_vector_type(4)));
typedef float f32x4 __attribute__((ext_vector_type(4)));

__device__ __forceinline__ float bfdec(unsigned short u) {
  return __uint_as_float(((unsigned)u) << 16);
}
__device__ __forceinline__ unsigned short f2h(float x) {
  _Float16 h = (_Float16)x;
  return __builtin_bit_cast(unsigned short, h);
}

// 2-wide f16 dot with f32 accumulator (v_dot2_f32_f16)
#if __has_builtin(__builtin_amdgcn_fdot2)
#define DOT2(a, b, c) __builtin_amdgcn_fdot2((a), (b), (c), false)
#else
#define DOT2(a, b, c) ((c) + (float)(a)[0] * (float)(b)[0] + (float)(a)[1] * (float)(b)[1])
#endif
#define D2(v, k) __builtin_shufflevector((v), (v), 2 * (k), 2 * (k) + 1)

// async global->LDS, 16B per lane (dest = wave-uniform base + lane*16)
__device__ __forceinline__ void gl_lds16(const _Float16* g, _Float16* l) {
  __builtin_amdgcn_global_load_lds(
      (const __attribute__((address_space(1))) void*)g,
      (__attribute__((address_space(3))) void*)l, 16, 0, 0);
}

// ---------------- dtype detector ----------------
__global__ __launch_bounds__(256) void detect_kernel(const unsigned short* __restrict__ raw,
                                                     float* __restrict__ flag) {
  __shared__ float sm[256];
  float mx = 0.f;
  for (int i = threadIdx.x; i < 2048; i += 256) mx = fmaxf(mx, fabsf(bfdec(raw[2 * i])));
  sm[threadIdx.x] = mx;
  __syncthreads();
  for (int s = 128; s > 0; s >>= 1) {
    if (threadIdx.x < s) sm[threadIdx.x] = fmaxf(sm[threadIdx.x], sm[threadIdx.x + s]);
    __syncthreads();
  }
  if (threadIdx.x == 0) flag[0] = (sm[0] > 1000.f) ? 1.f : 0.f;
}

// ---------------- convert all inputs to fp32 + f16 shadow in ONE pass ----------------
struct CvtArgs { const void* src[NARR]; int size[NARR]; int off[NARR]; };

__global__ __launch_bounds__(256) void convert_kernel(CvtArgs a, const float* __restrict__ flag,
                                                      float* __restrict__ dst,
                                                      _Float16* __restrict__ dsth) {
  int i = blockIdx.y;
  int sz = a.size[i];
  bool isf32 = flag[0] > 0.5f;
  const float* sf = (const float*)a.src[i];
  const unsigned short* sh = (const unsigned short*)a.src[i];
  float* d = dst + a.off[i];
  _Float16* dh = dsth + a.off[i];
  for (int j = blockIdx.x * 256 + threadIdx.x; j < sz; j += gridDim.x * 256) {
    float v = isf32 ? sf[j] : bfdec(sh[j]);
    d[j] = v;
    dh[j] = (_Float16)v;
  }
}

// ---------------- encoder: 16 nodes per 256-thread block, 8 outputs/thread ----------------
__global__ __launch_bounds__(256) void encoder_kernel(const float* __restrict__ nf,
    const float* __restrict__ encW, const float* __restrict__ encb, _Float16* __restrict__ Xh) {
  int tid = threadIdx.x;
  int v = blockIdx.x * 16 + (tid >> 4);
  int d0 = (tid & 15) << 3;
  int n = v % NN;
  float f[14];
#pragma unroll
  for (int i = 0; i < 10; i++) f[i] = nf[(size_t)v * 10 + i];
  f[10] = (n < 7) ? 1.f : 0.f;
  f[11] = (n == 7) ? 1.f : 0.f;
  f[12] = (n == 8) ? 1.f : 0.f;
  f[13] = fabsf((float)(n - 7));
  half8 o;
#pragma unroll
  for (int j = 0; j < 8; j++) {
    int d = d0 + j;
    const float* w = &encW[((size_t)n * 128 + d) * 14];
    float s = encb[n * 128 + d];
#pragma unroll
    for (int i = 0; i < 14; i++) s = fmaf(f[i], w[i], s);
    o[j] = (_Float16)s;
  }
  *(half8*)&Xh[(size_t)v * LDX + d0] = o;
}

// ---------------- fill ----------------
__global__ __launch_bounds__(256) void fill_kernel(const float* __restrict__ nf,
                                                   float* __restrict__ fill) {
  __shared__ float sx[256], sy[256], sz[256];
  int tid = threadIdx.x;
  float ax = 0.f, ay = 0.f, az = 0.f;
  for (int p = tid; p < BB * NN; p += 256) {
    int b = p / NN, n = p - b * NN;
    size_t late  = (((size_t)b * TT + (TT - 1)) * NN + n) * 10;
    size_t early = (((size_t)b * TT) * NN + n) * 10;
    ax += nf[late + 0] - nf[early + 0];
    ay += nf[late + 1] - nf[early + 1];
    az += nf[late + 2] - nf[early + 2];
  }
  sx[tid] = ax; sy[tid] = ay; sz[tid] = az;
  __syncthreads();
  for (int s = 128; s > 0; s >>= 1) {
    if (tid < s) { sx[tid] += sx[tid + s]; sy[tid] += sy[tid + s]; sz[tid] += sz[tid + s]; }
    __syncthreads();
  }
  if (tid == 0) { fill[0] = sx[0] / E_REAL; fill[1] = sy[0] / E_REAL; fill[2] = sz[0] / E_REAL; }
}

// ================= barrier-free pipelined MFMA GEMM =================
// 32 rows x 256 cols per block, 256 threads. Each wave owns output cols
// [wv*64, wv*64+64): it stages ONLY those W rows into its private LDS span
// (double-buffered, global_load_lds 16B, XOR-swizzled k-chunks) and loads its
// A fragments global->VGPR directly (prefetched 1 k-step ahead). No barriers;
// per-wave counted s_waitcnt vmcnt(6) only.
#define BUFH 8192   // halfs per buffer: 4 waves * 64 rows * 32 k

__device__ __forceinline__ void mfma_gemm_pipe(const _Float16* __restrict__ x,
    const _Float16* __restrict__ W, int K, int row0, int tid,
    _Float16* shB, f32x4 (&acc)[2][4]) {
  const int lane = tid & 63, wv = tid >> 6;
  const int quad = lane >> 4, mrow = lane & 15;
  const int brow = lane >> 2;                          // row within 16-row instr span
  const int bchunk = (lane & 3) ^ ((lane >> 3) & 3);   // swizzled source k-chunk
  const int rchunk = quad ^ ((mrow >> 1) & 3);         // swizzled read chunk
  const _Float16* wsrc = W + (size_t)(wv * 64 + brow) * K + bchunk * 8;
  const _Float16* a0p = x + (size_t)(row0 + mrow) * LDX + quad * 8;
  const _Float16* a1p = x + (size_t)(row0 + 16 + mrow) * LDX + quad * 8;
  _Float16* myB = shB + wv * 2048;                     // per-wave span (64*32)
  const int NK = K >> 5;

  // prologue: stage k-step 0 (4x gl_lds + 2x A reg loads = 6 vm ops)
#pragma unroll
  for (int i = 0; i < 4; i++)
    gl_lds16(wsrc + (size_t)i * 16 * K, myB + i * 512);
  half8 a0c = *(const half8*)a0p;
  half8 a1c = *(const half8*)a1p;
  half8 a0n = a0c, a1n = a1c;

  for (int t = 0; t < NK; t++) {
    if (t + 1 < NK) {
      const int kn = (t + 1) << 5;
      _Float16* nb = myB + ((t + 1) & 1) * BUFH;
#pragma unroll
      for (int i = 0; i < 4; i++)
        gl_lds16(wsrc + (size_t)i * 16 * K + kn, nb + i * 512);
      a0n = *(const half8*)(a0p + kn);
      a1n = *(const half8*)(a1p + kn);
      // 6 newest (k-step t+1) may stay in flight; everything older has landed
      asm volatile("s_waitcnt vmcnt(6)" ::: "memory");
    } else {
      asm volatile("s_waitcnt vmcnt(0)" ::: "memory");
    }
    __builtin_amdgcn_sched_barrier(0);
    const _Float16* bb = myB + (t & 1) * BUFH;
    half8 b0 = *(const half8*)&bb[(0 * 16 + mrow) * 32 + rchunk * 8];
    half8 b1 = *(const half8*)&bb[(1 * 16 + mrow) * 32 + rchunk * 8];
    half8 b2 = *(const half8*)&bb[(2 * 16 + mrow) * 32 + rchunk * 8];
    half8 b3 = *(const half8*)&bb[(3 * 16 + mrow) * 32 + rchunk * 8];
    acc[0][0] = __builtin_amdgcn_mfma_f32_16x16x32_f16(a0c, b0, acc[0][0], 0, 0, 0);
    acc[0][1] = __builtin_amdgcn_mfma_f32_16x16x32_f16(a0c, b1, acc[0][1], 0, 0, 0);
    acc[0][2] = __builtin_amdgcn_mfma_f32_16x16x32_f16(a0c, b2, acc[0][2], 0, 0, 0);
    acc[0][3] = __builtin_amdgcn_mfma_f32_16x16x32_f16(a0c, b3, acc[0][3], 0, 0, 0);
    acc[1][0] = __builtin_amdgcn_mfma_f32_16x16x32_f16(a1c, b0, acc[1][0], 0, 0, 0);
    acc[1][1] = __builtin_amdgcn_mfma_f32_16x16x32_f16(a1c, b1, acc[1][1], 0, 0, 0);
    acc[1][2] = __builtin_amdgcn_mfma_f32_16x16x32_f16(a1c, b2, acc[1][2], 0, 0, 0);
    acc[1][3] = __builtin_amdgcn_mfma_f32_16x16x32_f16(a1c, b3, acc[1][3], 0, 0, 0);
    a0c = a0n; a1c = a1n;
  }
}

// write acc (+bias) into epilogue LDS buffer as f16.  C/D map: col=lane&15, row=quad*4+reg
#define ACC32_TO_EPI(ACC, EPI, BIASPTR)                                         \
  {                                                                             \
    int lane_ = tid & 63, wv_ = tid >> 6, quad_ = lane_ >> 4, mrow_ = lane_ & 15; \
    _Pragma("unroll")                                                           \
    for (int rt = 0; rt < 2; rt++)                                              \
      _Pragma("unroll")                                                         \
      for (int ct = 0; ct < 4; ct++) {                                          \
        int col = wv_ * 64 + ct * 16 + mrow_;                                   \
        float bs_ = BIASPTR[col];                                               \
        _Pragma("unroll")                                                       \
        for (int r = 0; r < 4; r++)                                             \
          EPI[rt * 16 + quad_ * 4 + r][col] = f2h(ACC[rt][ct][r] + bs_);        \
      }                                                                         \
  }                                                                             \
  __syncthreads();

// ---------------- XL = X @ lW.T + lb -> f16 ----------------
__global__ __launch_bounds__(256, 4) void gemm_xl_kernel(const _Float16* __restrict__ x, int K,
    const _Float16* __restrict__ W, const float* __restrict__ bias, _Float16* __restrict__ XL) {
  __shared__ union { _Float16 B[2 * BUFH]; unsigned short epi[32][264]; } sh;
  int tid = threadIdx.x;
  int row0 = blockIdx.x * 32;
  f32x4 acc[2][4] = {};
  mfma_gemm_pipe(x, W, K, row0, tid, sh.B, acc);
  __syncthreads();                      // epi overlays B: all waves' B reads done
  ACC32_TO_EPI(acc, sh.epi, bias)
  int r = tid >> 3, cbase = (tid & 7) << 5;
#pragma unroll
  for (int j = 0; j < 4; j++)
    *(uint4*)&XL[(size_t)(row0 + r) * LDX + cbase + (j << 3)] =
        *(const uint4*)&sh.epi[r][cbase + (j << 3)];
}

// ============ fused per-layer kernel: XR GEMM + edges/softmax/agg (LDS) + sW GEMM + LN/SiLU ============
__global__ __launch_bounds__(256, 4) void fused_kernel(_Float16* __restrict__ Xh, int K,
    const _Float16* __restrict__ rW, const float* __restrict__ rb,
    const _Float16* __restrict__ XL, const float* __restrict__ nf, const float* __restrict__ fill,
    const _Float16* __restrict__ atth, const _Float16* __restrict__ ewh,
    const _Float16* __restrict__ sW, const float* __restrict__ sb,
    const float* __restrict__ gamma, const float* __restrict__ beta,
    float* pool_out, int do_pool) {
  __shared__ struct {
    union { _Float16 B[2 * BUFH]; float pacc[4][256]; } st;   // 32768 B
    unsigned short epi[32][264];                              // 16896 B
  } sh;
  int tid = threadIdx.x;
  int row0 = blockIdx.x * 32;
  int wave = tid >> 6, lane = tid & 63;

  // ---- phase 1: XR = X @ rW.T + rb -> epi ----
  {
    f32x4 acc[2][4] = {};
    mfma_gemm_pipe(Xh, rW, K, row0, tid, sh.st.B, acc);
    ACC32_TO_EPI(acc, sh.epi, rb)       // epi distinct from B; trailing barrier syncs all
  }

  // ---- phase 2: edge logits + softmax + aggregation (AGG overwrites epi in place) ----
  {
    int g = lane >> 4;          // node sub-index (0..3)
    int l = lane & 15;          // channel slab: 16 ch per lane
    int ch0 = l << 4;
    half8 att_lo = *(const half8*)&atth[ch0];
    half8 att_hi = *(const half8*)&atth[ch0 + 8];
    half8 ew0l, ew1l, ew2l, ew0h, ew1h, ew2h;
#pragma unroll
    for (int j = 0; j < 8; j++) {
      ew0l[j] = ewh[(ch0 + j) * 3 + 0];      ew0h[j] = ewh[(ch0 + 8 + j) * 3 + 0];
      ew1l[j] = ewh[(ch0 + j) * 3 + 1];      ew1h[j] = ewh[(ch0 + 8 + j) * 3 + 1];
      ew2l[j] = ewh[(ch0 + j) * 3 + 2];      ew2h[j] = ewh[(ch0 + 8 + j) * 3 + 2];
    }
    float f0 = fill[0], f1 = fill[1], f2 = fill[2];
    for (int it = 0; it < 2; it++) {
      int r = wave * 8 + it * 4 + g;
      int v = row0 + r;
      int n = v % NN;
      int t = (v / NN) & 63;
      int srcs[4] = { v, (n > 0) ? v - 1 : v, (n < NN - 1) ? v + 1 : v, (t > 0) ? v - NN : v };
      bool valid[4] = { true, n > 0, n < NN - 1, t > 0 };
      float px = nf[(size_t)v * 10 + 0];
      float py = nf[(size_t)v * 10 + 1];
      float pz = nf[(size_t)v * 10 + 2];
      _Float16* erow = (_Float16*)sh.epi[r];
      half8 xr_lo = *(const half8*)&erow[ch0];
      half8 xr_hi = *(const half8*)&erow[ch0 + 8];
      half8 xls[4][2];
      float lg[4];
#pragma unroll
      for (int e = 0; e < 4; e++) {
        int s = srcs[e];
        float a0, a1, a2;
        if (e == 0) { a0 = f0; a1 = f1; a2 = f2; }
        else {
          a0 = px - nf[(size_t)s * 10 + 0];
          a1 = py - nf[(size_t)s * 10 + 1];
          a2 = pz - nf[(size_t)s * 10 + 2];
        }
        _Float16 h0 = (_Float16)a0, h1 = (_Float16)a1, h2 = (_Float16)a2;
        xls[e][0] = *(const half8*)&XL[(size_t)s * LDX + ch0];
        xls[e][1] = *(const half8*)&XL[(size_t)s * LDX + ch0 + 8];
        half8 mlo = (xr_lo + xls[e][0]) + (ew0l * h0 + ew1l * h1 + ew2l * h2);
        half8 mhi = (xr_hi + xls[e][1]) + (ew0h * h0 + ew1h * h1 + ew2h * h2);
        mlo = __builtin_elementwise_max(mlo, mlo * (_Float16)0.2f);   // leaky 0.2 exact
        mhi = __builtin_elementwise_max(mhi, mhi * (_Float16)0.2f);
        float p = 0.f;
        p = DOT2(D2(mlo, 0), D2(att_lo, 0), p);
        p = DOT2(D2(mlo, 1), D2(att_lo, 1), p);
        p = DOT2(D2(mlo, 2), D2(att_lo, 2), p);
        p = DOT2(D2(mlo, 3), D2(att_lo, 3), p);
        p = DOT2(D2(mhi, 0), D2(att_hi, 0), p);
        p = DOT2(D2(mhi, 1), D2(att_hi, 1), p);
        p = DOT2(D2(mhi, 2), D2(att_hi, 2), p);
        p = DOT2(D2(mhi, 3), D2(att_hi, 3), p);
        p += __shfl_xor(p, 1);        // head spans 4 lanes (64 ch)
        p += __shfl_xor(p, 2);
        lg[e] = valid[e] ? p : -1e30f;
      }
      float mx = fmaxf(fmaxf(lg[0], lg[1]), fmaxf(lg[2], lg[3]));
      float w0 = __expf(lg[0] - mx), w1 = __expf(lg[1] - mx);
      float w2 = __expf(lg[2] - mx), w3 = __expf(lg[3] - mx);
      float inv = 1.f / (w0 + w1 + w2 + w3);
      float wv4[4] = { w0, w1, w2, w3 };
      half8 agg_lo = { 0, 0, 0, 0, 0, 0, 0, 0 };
      half8 agg_hi = { 0, 0, 0, 0, 0, 0, 0, 0 };
#pragma unroll
      for (int e = 0; e < 4; e++) {
        _Float16 wh = (_Float16)(wv4[e] * inv);   // invalid edges: exactly 0
        agg_lo = agg_lo + xls[e][0] * wh;
        agg_hi = agg_hi + xls[e][1] * wh;
      }
      // in-place: this lane is the only reader/writer of this slab
      *(half8*)&erow[ch0] = agg_lo;
      *(half8*)&erow[ch0 + 8] = agg_hi;
    }
  }
  // note: no barrier needed before phase-3's K-loop (it touches only st.B,
  // per-wave private spans); barrier comes before the cross-wave epi reads.

  // ---- phase 3: XO = X @ sW.T + sb + AGG -> epi (in place) ----
  {
    f32x4 acc[2][4] = {};
    mfma_gemm_pipe(Xh, sW, K, row0, tid, sh.st.B, acc);
    __syncthreads();                   // all edge-phase AGG writes visible
    int quad_ = lane >> 4, mrow_ = lane & 15;
#pragma unroll
    for (int rt = 0; rt < 2; rt++)
#pragma unroll
      for (int ct = 0; ct < 4; ct++) {
        int col = wave * 64 + ct * 16 + mrow_;
        float bs = sb[col];
#pragma unroll
        for (int rr = 0; rr < 4; rr++) {
          int row = rt * 16 + quad_ * 4 + rr;
          _Float16 ag = *(const _Float16*)&sh.epi[row][col];
          sh.epi[row][col] = f2h(acc[rt][ct][rr] + bs + (float)ag);
        }
      }
  }
  __syncthreads();

  // ---- phase 4: LayerNorm + SiLU + write Xh (+ pool) ----
  {
    int cc = lane << 2;
    float gm[4], bt[4];
#pragma unroll
    for (int i = 0; i < 4; i++) { gm[i] = gamma[cc + i]; bt[i] = beta[cc + i]; }
    float psum[4] = { 0.f, 0.f, 0.f, 0.f };
    for (int k = 0; k < 8; k++) {
      int r = wave * 8 + k;
      int v = row0 + r;
      const _Float16* erow = (const _Float16*)sh.epi[r];
      half4 x4 = *(const half4*)&erow[cc];
      float xv[4] = { (float)x4[0], (float)x4[1], (float)x4[2], (float)x4[3] };
      float s1 = xv[0] + xv[1] + xv[2] + xv[3];
#pragma unroll
      for (int off = 1; off < 64; off <<= 1) s1 += __shfl_xor(s1, off);
      float mu = s1 * (1.f / 256.f);
      float s2 = 0.f;
#pragma unroll
      for (int i = 0; i < 4; i++) { float d = xv[i] - mu; s2 = fmaf(d, d, s2); }
#pragma unroll
      for (int off = 1; off < 64; off <<= 1) s2 += __shfl_xor(s2, off);
      float rs = rsqrtf(s2 * (1.f / 256.f) + 1e-5f);
      half4 o;
#pragma unroll
      for (int i = 0; i < 4; i++) {
        float y = (xv[i] - mu) * rs * gm[i] + bt[i];
        float z = y * (1.f / (1.f + __expf(-y)));   // SiLU
        o[i] = (_Float16)z;
        psum[i] += z;
      }
      *(half4*)&Xh[(size_t)v * LDX + cc] = o;
    }
    if (do_pool) {
      __syncthreads();                 // B reads all done; reuse st as pacc
#pragma unroll
      for (int i = 0; i < 4; i++) sh.st.pacc[wave][cc + i] = psum[i];
      __syncthreads();
      if (wave == 0) {
        int b = row0 / 576;            // 576 = 9*64: block fully within one batch
#pragma unroll
        for (int i = 0; i < 4; i++) {
          float s = sh.st.pacc[0][cc + i] + sh.st.pacc[1][cc + i] +
                    sh.st.pacc[2][cc + i] + sh.st.pacc[3][cc + i];
          atomicAdd(&pool_out[b * 256 + cc + i], s * (1.f / 576.f));
        }
      }
    }
  }
}

extern "C" void kernel_launch(void* const* d_in, const int* in_sizes, int n_in,
                              void* d_out, int out_size, void* d_ws, size_t ws_size,
                              hipStream_t stream) {
  static const int kSize[NARR] = {
    737280, 16128, 1152,
    32768, 256, 32768, 256, 256, 768, 32768, 256, 256, 256,   // layer 0 (K=128)
    65536, 256, 65536, 256, 256, 768, 65536, 256, 256, 256,   // layer 1 (K=256)
    65536, 256, 65536, 256, 256, 768, 65536, 256, 256, 256    // layer 2 (K=256)
  };
  if (n_in != NARR || out_size != BB * 256) return;
  for (int i = 0; i < NARR; i++) if (in_sizes[i] != kSize[i]) return;

  CvtArgs ca;
  int off = 0;
  for (int i = 0; i < NARR; i++) { ca.src[i] = d_in[i]; ca.size[i] = kSize[i]; ca.off[i] = off; off += kSize[i]; }
  const int PRM_ELEMS = off;   // 1,252,992

  const size_t OFF_FLAG = 0;
  const size_t OFF_FILL = 16;
  const size_t OFF_PRM  = 256;
  const size_t OFF_PRMH = OFF_PRM + (size_t)PRM_ELEMS * 4;     // f16 shadow
  const size_t OFF_XL   = OFF_PRMH + (size_t)PRM_ELEMS * 2;    // XL f16
  const size_t OFF_XH   = OFF_XL + (size_t)NODES * LDX * 2;    // X f16
  const size_t NEED     = OFF_XH + (size_t)NODES * LDX * 2;    // ~80 MiB
  if (ws_size < NEED) return;

  char* ws = (char*)d_ws;
  float*     flag = (float*)(ws + OFF_FLAG);
  float*     fill = (float*)(ws + OFF_FILL);
  float*     prm  = (float*)(ws + OFF_PRM);
  _Float16*  prmh = (_Float16*)(ws + OFF_PRMH);
  _Float16*  XL   = (_Float16*)(ws + OFF_XL);
  _Float16*  Xh   = (_Float16*)(ws + OFF_XH);

  hipMemsetAsync(d_out, 0, (size_t)out_size * 4, stream);   // pool accumulator
  detect_kernel<<<1, 256, 0, stream>>>((const unsigned short*)d_in[0], flag);
  convert_kernel<<<dim3(360, NARR), 256, 0, stream>>>(ca, flag, prm, prmh);

  const float* nf   = prm + ca.off[0];
  const float* encW = prm + ca.off[1];
  const float* encb = prm + ca.off[2];

  encoder_kernel<<<NODES / 16, 256, 0, stream>>>(nf, encW, encb, Xh);
  fill_kernel<<<1, 256, 0, stream>>>(nf, fill);

  int K = 128;
  for (int L = 0; L < 3; L++) {
    const _Float16* lWh = prmh + ca.off[3 + L * 10 + 0];
    const float*    lb  = prm  + ca.off[3 + L * 10 + 1];
    const _Float16* rWh = prmh + ca.off[3 + L * 10 + 2];
    const float*    rb  = prm  + ca.off[3 + L * 10 + 3];
    const _Float16* atth= prmh + ca.off[3 + L * 10 + 4];
    const _Float16* ewhp= prmh + ca.off[3 + L * 10 + 5];
    const _Float16* sWh = prmh + ca.off[3 + L * 10 + 6];
    const float*    sb  = prm  + ca.off[3 + L * 10 + 7];
    const float*    g   = prm  + ca.off[3 + L * 10 + 8];
    const float*    b   = prm  + ca.off[3 + L * 10 + 9];
    gemm_xl_kernel<<<NODES / 32, 256, 0, stream>>>(Xh, K, lWh, lb, XL);
    fused_kernel<<<NODES / 32, 256, 0, stream>>>(Xh, K, rWh, rb, XL, nf, fill, atth, ewhp,
                                                 sWh, sb, g, b, (float*)d_out, (L == 2) ? 1 : 0);
    K = 256;
  }
}